// Round 8
// baseline (467.106 us; speedup 1.0000x reference)
//
#include <hip/hip_runtime.h>
#include <math.h>

// GNNMLP via f16 MFMA, TRANSPOSED-ACTIVATION form. G=131072 groups x 6 agents.
// R6-verified algebra: for mfma_f32_16x16x16_f16, D layout (col=lane&15,
//   row=quad*4+reg) == operand layout (n=lane&15, k=quad*4+j), so a D-frag
//   cvt'd to f16 IS the next layer's B-operand. All layers computed transposed
//   (D = W^T x X^T, activations [feature][group], group-in-lane). Zero data
//   LDS, zero transposes (R6/R7: bank conflicts = 0).
// ROUND-8: R0-R7 plateau at 140-240 us across 5 structures. Accounting: each
//   wave issues ~10k cycles but lives ~100k+ -- >90% stalled on its own serial
//   13-phase chain (loadW->wait->MFMA->cvt->next), and 2-4 waves/SIMD can't
//   hide it. Occupancy is capped by VGPR/LDS (R1-R3), so add ILP instead:
//   TWO independent 16-group chains per wave (all activation state [2],
//   compile-time-unrolled indices). Each phase's W-load is SHARED by both
//   chains (same 8 dwordx4 serve 2x MFMAs) and every latency now overlaps
//   with the sibling chain. Grid: 1024 blocks x 4 waves x 32 groups.
// OCCUPANCY GOVERNOR (R3-proven mechanism, re-tuned): peak live regs ~160 ->
//   need 170-VGPR budget = 3 waves/EU: block=256 (4 waves), LDS pad 54272 B
//   (floor(163840/54272)=3 blocks/CU), launch_bounds(256,3). LDS caps
//   occupancy so the allocator has no incentive to squeeze below ~170.
// prep_weights: img = W^T A-frags, PAIRED packing: matrix m, pair (mt,kp):
//   img[m*4096 + (mt*2+kp)*512 + lane*8 + t], t=0..3 -> kt=2kp, t=4..7 ->
//   kt=2kp+1; element = W[k][n], k=kt*16+(lane>>4)*4+(t&3), n=mt*16+(lane&15).
//   Head: 2 ty sets at 12*4096 + ty*1024 (D rows 0..9 = ty0 slots, 10..11 =
//   ty1, rest zero, C-chained over ty).
// Layouts (m89/m120-verified family, K=16 variant):
//   A[m][k]: m=lane&15, k=(lane>>4)*4+j   B[k][n]: n=lane&15, k=(lane>>4)*4+j
//   C/D:     col=lane&15, row=(lane>>4)*4+reg

typedef _Float16 f16;
typedef __fp16   fp16x2_t __attribute__((ext_vector_type(2)));
typedef _Float16 half4_t  __attribute__((ext_vector_type(4)));
typedef _Float16 half8_t  __attribute__((ext_vector_type(8)));
typedef float    float4_t __attribute__((ext_vector_type(4)));

#define NW 4            // waves per block
#define LDS_PAD_F 13568 // 54272 B: floor(163840/54272) = 3 blocks/CU cap

#define MFMA16(A,B,C) __builtin_amdgcn_mfma_f32_16x16x16f16((A),(B),(C),0,0,0)

__device__ __forceinline__ float fast_tanh(float x) {
    float e = __expf(2.0f * x);
    return 1.0f - 2.0f / (e + 1.0f);
}

__device__ __forceinline__ float4_t max4(float4_t a, float4_t b) {
    float4_t r;
    r[0] = fmaxf(a[0], b[0]); r[1] = fmaxf(a[1], b[1]);
    r[2] = fmaxf(a[2], b[2]); r[3] = fmaxf(a[3], b[3]);
    return r;
}

__device__ __forceinline__ float4_t bcast4(float v) {
    float4_t r; r[0] = v; r[1] = v; r[2] = v; r[3] = v; return r;
}

__device__ __forceinline__ half4_t flo(half8_t v) {
    half4_t r; r[0] = v[0]; r[1] = v[1]; r[2] = v[2]; r[3] = v[3]; return r;
}
__device__ __forceinline__ half4_t fhi(half8_t v) {
    half4_t r; r[0] = v[4]; r[1] = v[5]; r[2] = v[6]; r[3] = v[7]; return r;
}

// f32x4 -> f16x4 via 2 packed cvt
__device__ __forceinline__ half4_t cvt4(float4_t v) {
    fp16x2_t p0 = __builtin_amdgcn_cvt_pkrtz(v[0], v[1]);
    fp16x2_t p1 = __builtin_amdgcn_cvt_pkrtz(v[2], v[3]);
    half4_t r;
    r[0] = (f16)p0[0]; r[1] = (f16)p0[1]; r[2] = (f16)p1[0]; r[3] = (f16)p1[1];
    return r;
}

// ---------------- prep: W^T A-fragment image (paired packing) ----------------
__global__ void prep_weights(const float* __restrict__ Wp1, const float* __restrict__ Ws1,
                             const float* __restrict__ Wn1, const float* __restrict__ Wp2,
                             const float* __restrict__ Ws2, const float* __restrict__ Wn2,
                             const float* __restrict__ MW1, const float* __restrict__ MW2,
                             const float* __restrict__ MW3, const float* __restrict__ MW4,
                             f16* __restrict__ img)
{
    const int m = blockIdx.x;
    const int tid = threadIdx.x;
    if (m < 12) {
        const float* src;
        switch (m) {
            case 0: src = Wp1; break;  case 1: src = Ws1; break;
            case 2: src = Wn1; break;  case 3: src = Wp2; break;
            case 4: src = Ws2; break;  case 5: src = Wn2; break;
            case 6: src = MW1; break;  case 7: src = MW2; break;
            case 8: src = MW3; break;  case 9: src = MW1 + 4096; break;
            case 10: src = MW2 + 4096; break; default: src = MW3 + 4096; break;
        }
        for (int e = tid; e < 4096; e += 256) {
            const int p = e >> 9, mt = p >> 1, kp = p & 1;
            const int o = e & 511, lane = o >> 3, j8 = o & 7;
            const int kt = kp * 2 + (j8 >> 2), j = j8 & 3;
            const int k = kt * 16 + (lane >> 4) * 4 + j;
            const int n = mt * 16 + (lane & 15);
            img[m * 4096 + e] = (f16)src[k * 64 + n];
        }
    } else {
        for (int e = tid; e < 2048; e += 256) {
            const int ty = e >> 10, o = e & 1023;
            const int kp = o >> 9, oo = o & 511, lane = oo >> 3, j8 = oo & 7;
            const int kt = kp * 2 + (j8 >> 2), j = j8 & 3;
            const int k = kt * 16 + (lane >> 4) * 4 + j;
            const int mm = lane & 15;
            float v = 0.f;
            if (ty == 0) { if (mm < 10) v = MW4[k * 2 + (mm & 1)]; }
            else         { if (mm == 10 || mm == 11) v = MW4[128 + k * 2 + (mm & 1)]; }
            img[12 * 4096 + e] = (f16)v;
        }
    }
}

// ---------------- main fused kernel ----------------
__global__ __launch_bounds__(256, 3)
void gnn_mfma(const float* __restrict__ obs, const f16* __restrict__ img,
              const float* __restrict__ bp1, const float* __restrict__ b1,
              const float* __restrict__ bp2, const float* __restrict__ b2,
              const float* __restrict__ Mb1, const float* __restrict__ Mb2,
              const float* __restrict__ Mb3, const float* __restrict__ Mb4,
              float* __restrict__ out)
{
    // pure occupancy governor (no data LDS)
    __shared__ __align__(16) float smem[LDS_PAD_F];
    const int tid  = threadIdx.x;
    if (tid == 0) { volatile float* g = smem; g[0] = 0.f; }

    const int w    = __builtin_amdgcn_readfirstlane(tid >> 6);
    const int l    = tid & 63;
    const int col  = l & 15;   // group within sub-batch (operand n / D col)
    const int quad = l >> 4;   // feature sub-block (operand k / D row: quad*4+r)

    const int wid = blockIdx.x * NW + w;
    const int g0  = wid * 32;  // 2 sub-batches of 16 groups
    const float* orow[2];
    orow[0] = obs + (size_t)(g0 + col) * 384 + quad * 4;
    orow[1] = obs + (size_t)(g0 + 16 + col) * 384 + quad * 4;

    // W^T A-frag banks, reused across phases: Wd[mt][kp] = {kt=2kp, 2kp+1}
    half8_t Wm[4][2], Wn[4][2];
    auto loadW = [&](half8_t (&Wd)[4][2], int baseH) {
        #pragma unroll
        for (int mt = 0; mt < 4; ++mt)
            #pragma unroll
            for (int kp = 0; kp < 2; ++kp)
                Wd[mt][kp] = *(const half8_t*)(img + baseH + (mt * 2 + kp) * 512 + l * 8);
    };
    auto wf = [&](const half8_t (&Wd)[4][2], int mt, int kt) -> half4_t {
        return (kt & 1) ? fhi(Wd[mt][kt >> 1]) : flo(Wd[mt][kt >> 1]);
    };

    // ---- phase A: conv1 pool  n1 = max_a relu(Wp1^T obs_a^T + bp1) ----
    loadW(Wm, 0);
    float4_t bq[4];
    #pragma unroll
    for (int mt = 0; mt < 4; ++mt)
        bq[mt] = *(const float4_t*)(bp1 + mt * 16 + quad * 4);

    float4_t n1[2][4];
    #pragma unroll
    for (int b = 0; b < 2; ++b)
        #pragma unroll
        for (int mt = 0; mt < 4; ++mt) n1[b][mt] = bcast4(0.f);
    {
        float4_t ox[2][4];   // 1-deep raw-f32 obs prefetch (cold HBM)
        #pragma unroll
        for (int b = 0; b < 2; ++b)
            #pragma unroll
            for (int kt = 0; kt < 4; ++kt)
                ox[b][kt] = *(const float4_t*)(orow[b] + kt * 16);
        #pragma unroll
        for (int a = 0; a < 6; ++a) {
            half4_t ob[2][4];
            #pragma unroll
            for (int b = 0; b < 2; ++b)
                #pragma unroll
                for (int kt = 0; kt < 4; ++kt) ob[b][kt] = cvt4(ox[b][kt]);
            if (a < 5) {
                #pragma unroll
                for (int b = 0; b < 2; ++b)
                    #pragma unroll
                    for (int kt = 0; kt < 4; ++kt)
                        ox[b][kt] = *(const float4_t*)(orow[b] + (a + 1) * 64 + kt * 16);
            }
            #pragma unroll
            for (int mt = 0; mt < 4; ++mt) {
                #pragma unroll
                for (int b = 0; b < 2; ++b) {
                    float4_t acc = bq[mt];
                    #pragma unroll
                    for (int kt = 0; kt < 4; ++kt)
                        acc = MFMA16(wf(Wm, mt, kt), ob[b][kt], acc);
                    n1[b][mt] = max4(n1[b][mt], acc);   // relu folded (init 0)
                }
            }
        }
    }

    // ---- c = Wn1^T n1^T + b1 (register chaining) ----
    half4_t n1h[2][4];
    #pragma unroll
    for (int b = 0; b < 2; ++b)
        #pragma unroll
        for (int kt = 0; kt < 4; ++kt) n1h[b][kt] = cvt4(n1[b][kt]);
    float4_t c[2][4];
    {
        int bW = 2 * 4096;
        asm volatile("" : "+s"(bW));   // phase-granular opacity
        loadW(Wm, bW);
        #pragma unroll
        for (int mt = 0; mt < 4; ++mt) {
            const float4_t bb = *(const float4_t*)(b1 + mt * 16 + quad * 4);
            #pragma unroll
            for (int b = 0; b < 2; ++b) {
                float4_t acc = bb;
                #pragma unroll
                for (int kt = 0; kt < 4; ++kt)
                    acc = MFMA16(wf(Wm, mt, kt), n1h[b][kt], acc);
                c[b][mt] = acc;
            }
        }
    }

    // ---- phase B (fused): per agent h_a = tanh(Ws1^T obs_a^T + c);
    //      hbar += h_a; n2m = max_a(Wp2^T h_a^T)  [bias+relu folded at end] ----
    {
        int bWs = 1 * 4096, bWp = 3 * 4096;
        asm volatile("" : "+s"(bWs), "+s"(bWp));
        loadW(Wm, bWs);
        loadW(Wn, bWp);
    }
    float4_t hbar[2][4], n2m[2][4];
    #pragma unroll
    for (int b = 0; b < 2; ++b)
        #pragma unroll
        for (int mt = 0; mt < 4; ++mt) {
            hbar[b][mt] = bcast4(0.f);
            n2m[b][mt]  = bcast4(-3.0e38f);
        }
    #pragma unroll
    for (int a = 0; a < 6; ++a) {
        half4_t ob[2][4];
        #pragma unroll
        for (int b = 0; b < 2; ++b)
            #pragma unroll
            for (int kt = 0; kt < 4; ++kt)
                ob[b][kt] = cvt4(*(const float4_t*)(orow[b] + a * 64 + kt * 16)); // L2-hot
        half4_t hh[2][4];
        #pragma unroll
        for (int mt = 0; mt < 4; ++mt) {
            #pragma unroll
            for (int b = 0; b < 2; ++b) {
                float4_t acc = c[b][mt];
                #pragma unroll
                for (int kt = 0; kt < 4; ++kt)
                    acc = MFMA16(wf(Wm, mt, kt), ob[b][kt], acc);
                #pragma unroll
                for (int r = 0; r < 4; ++r) acc[r] = fast_tanh(acc[r]);
                hbar[b][mt] += acc;
                hh[b][mt] = cvt4(acc);
            }
        }
        #pragma unroll
        for (int mt = 0; mt < 4; ++mt) {
            #pragma unroll
            for (int b = 0; b < 2; ++b) {
                float4_t q = bcast4(0.f);
                #pragma unroll
                for (int kt = 0; kt < 4; ++kt)
                    q = MFMA16(wf(Wn, mt, kt), hh[b][kt], q);
                n2m[b][mt] = max4(n2m[b][mt], q);
            }
        }
    }
    // n2 = relu(max_a(...) + bp2)   [max/+bias/relu commute: bias uniform in a]
    float4_t n2[2][4];
    #pragma unroll
    for (int mt = 0; mt < 4; ++mt) {
        const float4_t bb = *(const float4_t*)(bp2 + mt * 16 + quad * 4);
        #pragma unroll
        for (int b = 0; b < 2; ++b)
            n2[b][mt] = max4(n2m[b][mt] + bb, bcast4(0.f));
    }

    // ---- res = Ws2^T hbar^T + Wn2^T n2^T + b2 (two resident-W passes) ----
    half4_t hbh[2][4], n2h[2][4];
    #pragma unroll
    for (int b = 0; b < 2; ++b)
        #pragma unroll
        for (int kt = 0; kt < 4; ++kt) {
            hbh[b][kt] = cvt4(hbar[b][kt] * (1.0f / 6.0f));
            n2h[b][kt] = cvt4(n2[b][kt]);
        }
    float4_t rr[2][4];
    {
        int b4 = 4 * 4096;
        asm volatile("" : "+s"(b4));
        loadW(Wm, b4);
        #pragma unroll
        for (int mt = 0; mt < 4; ++mt) {
            const float4_t bb = *(const float4_t*)(b2 + mt * 16 + quad * 4);
            #pragma unroll
            for (int b = 0; b < 2; ++b) {
                float4_t acc = bb;
                #pragma unroll
                for (int kt = 0; kt < 4; ++kt)
                    acc = MFMA16(wf(Wm, mt, kt), hbh[b][kt], acc);
                rr[b][mt] = acc;
            }
        }
    }
    {
        int b5 = 5 * 4096;
        asm volatile("" : "+s"(b5));
        loadW(Wm, b5);
        #pragma unroll
        for (int mt = 0; mt < 4; ++mt)
            #pragma unroll
            for (int b = 0; b < 2; ++b)
                #pragma unroll
                for (int kt = 0; kt < 4; ++kt)
                    rr[b][mt] = MFMA16(wf(Wm, mt, kt), n2h[b][kt], rr[b][mt]);
    }

    // ---- per-type 3-layer relu MLP, register-chained, W resident per layer ----
    half4_t x3h[2][2][4];   // [ty][b][kt]
    #pragma unroll
    for (int ty = 0; ty < 2; ++ty) {
        half4_t xh[2][4];
        #pragma unroll
        for (int b = 0; b < 2; ++b)
            #pragma unroll
            for (int kt = 0; kt < 4; ++kt) xh[b][kt] = cvt4(rr[b][kt]);
        #pragma unroll
        for (int layer = 0; layer < 3; ++layer) {
            int bb = (6 + ty * 3 + layer) * 4096;
            asm volatile("" : "+s"(bb));
            loadW(Wm, bb);
            const float* Mb = (layer == 0 ? Mb1 : layer == 1 ? Mb2 : Mb3) + ty * 64;
            float4_t nx[2][4];
            #pragma unroll
            for (int mt = 0; mt < 4; ++mt) {
                const float4_t bv = *(const float4_t*)(Mb + mt * 16 + quad * 4);
                #pragma unroll
                for (int b = 0; b < 2; ++b) {
                    float4_t acc = bv;
                    #pragma unroll
                    for (int kt = 0; kt < 4; ++kt)
                        acc = MFMA16(wf(Wm, mt, kt), xh[b][kt], acc);
                    nx[b][mt] = max4(acc, bcast4(0.f));  // relu
                }
            }
            #pragma unroll
            for (int b = 0; b < 2; ++b)
                #pragma unroll
                for (int kt = 0; kt < 4; ++kt) xh[b][kt] = cvt4(nx[b][kt]);
        }
        #pragma unroll
        for (int b = 0; b < 2; ++b)
            #pragma unroll
            for (int kt = 0; kt < 4; ++kt) x3h[ty][b][kt] = xh[b][kt];
    }

    // ---- head: D rows 0..11 = 12 output slots, C-chained over both types ----
    float4_t d[2];
    d[0] = bcast4(0.f); d[1] = bcast4(0.f);
    {
        int bh = 12 * 4096;
        asm volatile("" : "+s"(bh));
        half8_t H0[2], H1[2];
        #pragma unroll
        for (int kp = 0; kp < 2; ++kp) {
            H0[kp] = *(const half8_t*)(img + bh + kp * 512 + l * 8);
            H1[kp] = *(const half8_t*)(img + bh + 1024 + kp * 512 + l * 8);
        }
        #pragma unroll
        for (int kt = 0; kt < 4; ++kt) {
            const half4_t f = (kt & 1) ? fhi(H0[kt >> 1]) : flo(H0[kt >> 1]);
            #pragma unroll
            for (int b = 0; b < 2; ++b) d[b] = MFMA16(f, x3h[0][b][kt], d[b]);
        }
        #pragma unroll
        for (int kt = 0; kt < 4; ++kt) {
            const half4_t f = (kt & 1) ? fhi(H1[kt >> 1]) : flo(H1[kt >> 1]);
            #pragma unroll
            for (int b = 0; b < 2; ++b) d[b] = MFMA16(f, x3h[1][b][kt], d[b]);
        }
    }

    // store: lane(quad<3) holds rows quad*4..+3 for its group ->
    // one coalesced float4 per lane per sub-batch
    if (quad < 3) {
        const float m00 = Mb4[0], m01 = Mb4[1], m10 = Mb4[2], m11 = Mb4[3];
        #pragma unroll
        for (int b = 0; b < 2; ++b) {
            float4_t v;
            #pragma unroll
            for (int r = 0; r < 4; ++r) {
                const int slot = quad * 4 + r;
                const float mb = (slot < 10) ? ((r & 1) ? m01 : m00)
                                             : ((r & 1) ? m11 : m10);
                v[r] = fast_tanh(d[b][r] + mb);
            }
            *(float4_t*)(out + (size_t)(g0 + b * 16 + col) * 12 + quad * 4) = v;
        }
    }
}

extern "C" void kernel_launch(void* const* d_in, const int* in_sizes, int n_in,
                              void* d_out, int out_size, void* d_ws, size_t ws_size,
                              hipStream_t stream)
{
    const float* obs = (const float*)d_in[0];
    const float* Wp1 = (const float*)d_in[1];
    const float* bp1 = (const float*)d_in[2];
    const float* Ws1 = (const float*)d_in[3];
    const float* Wn1 = (const float*)d_in[4];
    const float* b1  = (const float*)d_in[5];
    const float* Wp2 = (const float*)d_in[6];
    const float* bp2 = (const float*)d_in[7];
    const float* Ws2 = (const float*)d_in[8];
    const float* Wn2 = (const float*)d_in[9];
    const float* b2  = (const float*)d_in[10];
    const float* MW1 = (const float*)d_in[11];
    const float* Mb1 = (const float*)d_in[12];
    const float* MW2 = (const float*)d_in[13];
    const float* Mb2 = (const float*)d_in[14];
    const float* MW3 = (const float*)d_in[15];
    const float* Mb3 = (const float*)d_in[16];
    const float* MW4 = (const float*)d_in[17];
    const float* Mb4 = (const float*)d_in[18];
    float* out = (float*)d_out;
    f16* img = (f16*)d_ws;   // 12*4096 + 2048 = 51200 halfs = 100 KB

    hipLaunchKernelGGL(prep_weights, dim3(13), dim3(256), 0, stream,
                       Wp1, Ws1, Wn1, Wp2, Ws2, Wn2, MW1, MW2, MW3, MW4, img);
    // 1024 blocks x 4 waves x 32 groups = 131072
    hipLaunchKernelGGL(gnn_mfma, dim3(1024), dim3(256), 0, stream,
                       obs, img, bp1, b1, bp2, b2, Mb1, Mb2, Mb3, Mb4, out);
}